// Round 2
// baseline (998.426 us; speedup 1.0000x reference)
//
#include <hip/hip_runtime.h>
#include <hip/hip_bf16.h>

#define Vn 25000
#define En 100000
#define NODE_IN 74
#define EDGE_IN 12
#define OUTD 64
#define EHID 128
#define NUM_STEPS 6

#define HPAD 68  // h_t row pitch (floats)

typedef __attribute__((ext_vector_type(8))) _Float16 half8;
typedef __attribute__((ext_vector_type(4))) float floatx4;

// h[v,o] = relu(node[v,:] @ Wp + bp)   [V,74]@[74,64]  (all fp32)
__global__ void proj_kernel(const float* __restrict__ node,
                            const float* __restrict__ Wp,
                            const float* __restrict__ bp,
                            float* __restrict__ h) {
  __shared__ float nf[NODE_IN];
  int v = blockIdx.x;
  int o = threadIdx.x;  // 64
  for (int i = o; i < NODE_IN; i += 64) nf[i] = node[(size_t)v * NODE_IN + i];
  __syncthreads();
  float acc = bp[o];
  for (int i = 0; i < NODE_IN; ++i) acc = fmaf(nf[i], Wp[i * OUTD + o], acc);
  h[(size_t)v * OUTD + o] = fmaxf(acc, 0.0f);
}

// f[e,k] = relu(edge[e,:] @ We1 + be1)   [E,12]@[12,128] fp32, stored f16
__global__ void edge_kernel(const float* __restrict__ ef,
                            const float* __restrict__ We1,
                            const float* __restrict__ be1,
                            _Float16* __restrict__ f) {
  __shared__ float es[EDGE_IN];
  int e = blockIdx.x;
  int k = threadIdx.x;  // 128
  if (k < EDGE_IN) es[k] = ef[(size_t)e * EDGE_IN + k];
  __syncthreads();
  float acc = be1[k];
  for (int j = 0; j < EDGE_IN; ++j) acc = fmaf(es[j], We1[j * EHID + k], acc);
  f[(size_t)e * EHID + k] = (_Float16)fmaxf(acc, 0.0f);
}

// Wave-coalesced B layout (f16): element at
//   g = ((((i*4 + c)*4 + s)*16 + l15)*4 + quad)*8 + j
// holds f16(We2[k = s*32+quad*8+j][col = i*64 + c*16 + l15]).
__global__ void w2r_kernel(const float* __restrict__ We2,
                           _Float16* __restrict__ w2s) {
  int g = blockIdx.x * 256 + threadIdx.x;  // < 524288
  int j = g & 7;
  int quad = (g >> 3) & 3;
  int l15 = (g >> 5) & 15;
  int s = (g >> 9) & 3;
  int wv = (g >> 11) & 3;
  int i = g >> 13;
  int k = s * 32 + quad * 8 + j;
  int col = i * 64 + wv * 16 + l15;
  w2s[g] = (_Float16)We2[(size_t)k * (OUTD * OUTD) + col];
}

// Fused per-step message kernel, i-split across waves:
// wave w accumulates partial msg over i in [16w, 16w+16) for ALL 64 output
// cols (64x64 partial per wave), so each A-scale (h_i * F) feeds 64 cols
// instead of 16 (4x less VALU). Two-stage LDS reduce-scatter then atomics.
__global__ __launch_bounds__(256, 2) void msg_kernel(
    const float* __restrict__ h,
    const _Float16* __restrict__ f,
    const _Float16* __restrict__ w2s,
    const int* __restrict__ src,
    const int* __restrict__ dst,
    const float* __restrict__ be2,
    float* __restrict__ agg) {
  // first 4352 floats: h_t[64][HPAD]; after h_t dies: 32KB reduce scratch.
  // __align__(16): smem is accessed through floatx4* (ds_*_b128 need 16B).
  __shared__ __align__(16) float smem[8192];
  __shared__ int s_dst[64];

  const int tid = threadIdx.x;
  const int wv = tid >> 6;        // wave 0..3 -> i-subset [16wv,16wv+16)
  const int lane = tid & 63;
  const int quad = lane >> 4;
  const int l15 = lane & 15;
  const int e0 = blockIdx.x * 64;

  if (tid < 64) {
    int e = e0 + tid;
    s_dst[tid] = (e < En) ? dst[e] : -1;
  }
  {
    int e = tid & 63;
    int ib = tid >> 6;  // i-block 0..3 (16 i's each)
    int eg = e0 + e;
    int sv = (eg < En) ? src[eg] : 0;
    const float4* hp = reinterpret_cast<const float4*>(h + (size_t)sv * OUTD + ib * 16);
    for (int c = 0; c < 4; ++c) {
      float4 val = hp[c];
      int i4 = ib * 16 + c * 4;
      smem[(i4 + 0) * HPAD + e] = val.x;
      smem[(i4 + 1) * HPAD + e] = val.y;
      smem[(i4 + 2) * HPAD + e] = val.z;
      smem[(i4 + 3) * HPAD + e] = val.w;
    }
  }
  __syncthreads();

  // A-fragments (f16): F rows for 4 row-tiles x 4 K-steps (i-invariant).
  // A[m=lane&15][k = s*32 + quad*8 + j]
  half8 afr[4][4];
#pragma unroll
  for (int t = 0; t < 4; ++t) {
    int e = e0 + t * 16 + l15;
    if (e >= En) e = En - 1;  // clamped rows suppressed at scatter
    const _Float16* fr = f + (size_t)e * EHID + quad * 8;
#pragma unroll
    for (int s = 0; s < 4; ++s)
      afr[t][s] = *reinterpret_cast<const half8*>(fr + s * 32);
  }

  const _Float16* w2l = w2s + l15 * 32 + quad * 8;  // lane offset

// load B frags for all 4 col-stripes at (i=II, s=SS) into named buffer B
#define LOADB4(B, II, SS)                                                   \
  {                                                                         \
    const _Float16* p_ = w2l + (size_t)(II) * 8192 + (SS) * 512;            \
    B[0] = *reinterpret_cast<const half8*>(p_);                             \
    B[1] = *reinterpret_cast<const half8*>(p_ + 2048);                      \
    B[2] = *reinterpret_cast<const half8*>(p_ + 4096);                      \
    B[3] = *reinterpret_cast<const half8*>(p_ + 6144);                      \
  }

  floatx4 acc[4][4];  // [row-tile t][col-stripe c]
  const floatx4 zero4 = (floatx4){0.f, 0.f, 0.f, 0.f};
#pragma unroll
  for (int t = 0; t < 4; ++t)
#pragma unroll
    for (int c = 0; c < 4; ++c) acc[t][c] = zero4;

  half8 b0[4], b1[4];
  const int ibase = wv * 16;
  LOADB4(b0, ibase, 0);

// one K-chunk: prefetch next B, scale A by h_i once, feed all 4 col-stripes
#define SSTEP(SS, CURB, NXTB, NI, NS)                                         \
  {                                                                           \
    LOADB4(NXTB, NI, NS);                                                     \
    _Pragma("unroll") for (int t = 0; t < 4; ++t) {                           \
      half8 as = afr[t][SS] * hb[t];                                          \
      acc[t][0] = __builtin_amdgcn_mfma_f32_16x16x32_f16(as, CURB[0], acc[t][0], 0, 0, 0); \
      acc[t][1] = __builtin_amdgcn_mfma_f32_16x16x32_f16(as, CURB[1], acc[t][1], 0, 0, 0); \
      acc[t][2] = __builtin_amdgcn_mfma_f32_16x16x32_f16(as, CURB[2], acc[t][2], 0, 0, 0); \
      acc[t][3] = __builtin_amdgcn_mfma_f32_16x16x32_f16(as, CURB[3], acc[t][3], 0, 0, 0); \
    }                                                                         \
  }

  for (int ii = 0; ii < 16; ++ii) {
    int iv = ibase + ii;
    half8 hb[4];
#pragma unroll
    for (int t = 0; t < 4; ++t) {
      _Float16 hf = (_Float16)smem[iv * HPAD + t * 16 + l15];
      hb[t] = (half8){hf, hf, hf, hf, hf, hf, hf, hf};
    }
    int nxi = (ii == 15) ? iv : iv + 1;  // clamp (harmless reload on last iter)
    SSTEP(0, b0, b1, iv, 1);
    SSTEP(1, b1, b0, iv, 2);
    SSTEP(2, b0, b1, iv, 3);
    SSTEP(3, b1, b0, nxi, 0);
  }

  // be2 contribution (exact 0 here, kept for generality): wave 0 owns all
  // cols pre-reduction, so add sum_i h[e,i]*be2[i*64+o] on wave 0 only.
  if (wv == 0) {
#pragma unroll
    for (int s = 0; s < 2; ++s) {
      half8 b2f[4];
#pragma unroll
      for (int c = 0; c < 4; ++c) {
        half8 v;
#pragma unroll
        for (int j = 0; j < 8; ++j)
          v[j] = (_Float16)be2[(s * 32 + quad * 8 + j) * 64 + c * 16 + l15];
        b2f[c] = v;
      }
#pragma unroll
      for (int t = 0; t < 4; ++t) {
        half8 ha;
#pragma unroll
        for (int j = 0; j < 8; ++j)
          ha[j] = (_Float16)smem[(s * 32 + quad * 8 + j) * HPAD + t * 16 + l15];
#pragma unroll
        for (int c = 0; c < 4; ++c)
          acc[t][c] = __builtin_amdgcn_mfma_f32_16x16x32_f16(ha, b2f[c], acc[t][c], 0, 0, 0);
      }
    }
  }

  // ---- cross-wave reduce-scatter (static indices only; wave-uniform branches)
  floatx4* scv = reinterpret_cast<floatx4*>(smem);

#define ST1(TG)                                                           \
  _Pragma("unroll") for (int c = 0; c < 4; ++c)                           \
      scv[wv * 512 + (((TG) & 1) * 4 + c) * 64 + lane] = acc[TG][c];
#define LD1(TK)                                                           \
  _Pragma("unroll") for (int c = 0; c < 4; ++c)                           \
      acc[TK][c] += scv[(wv ^ 1) * 512 + (((TK) & 1) * 4 + c) * 64 + lane];
#define ST2(TG)                                                           \
  _Pragma("unroll") for (int c = 0; c < 4; ++c)                           \
      scv[wv * 512 + c * 64 + lane] = acc[TG][c];
#define LD2(TK)                                                           \
  _Pragma("unroll") for (int c = 0; c < 4; ++c)                           \
      acc[TK][c] += scv[(wv ^ 2) * 512 + c * 64 + lane];
#define SCAT(TF)                                                          \
  {                                                                       \
    int rb = (TF) * 16 + quad * 4;                                        \
    _Pragma("unroll") for (int c = 0; c < 4; ++c) {                       \
      int col = c * 16 + l15;                                             \
      _Pragma("unroll") for (int r = 0; r < 4; ++r) {                     \
        int d = s_dst[rb + r];                                            \
        if (d >= 0) atomicAdd(&agg[(size_t)d * OUTD + col], acc[TF][c][r]); \
      }                                                                   \
    }                                                                     \
  }

  __syncthreads();  // h_t dead from here; smem becomes reduce scratch
  // stage 1: pairs (0,1),(2,3). even wave keeps rows t{0,1}, odd keeps t{2,3}
  if ((wv & 1) == 0) { ST1(2); ST1(3); } else { ST1(0); ST1(1); }
  __syncthreads();
  if ((wv & 1) == 0) { LD1(0); LD1(1); } else { LD1(2); LD1(3); }
  __syncthreads();
  // stage 2: pairs (0,2),(1,3). final tile: w0->t0, w2->t1, w1->t2, w3->t3
  if (wv == 0) { ST2(1); } else if (wv == 1) { ST2(3); }
  else if (wv == 2) { ST2(0); } else { ST2(2); }
  __syncthreads();
  if (wv == 0) { LD2(0); SCAT(0); }
  else if (wv == 1) { LD2(2); SCAT(2); }
  else if (wv == 2) { LD2(1); SCAT(1); }
  else { LD2(3); SCAT(3); }
}

// h_out = relu(agg + bias); re-zero agg; last step also writes fp32 d_out
__global__ void update_kernel(float* __restrict__ agg,
                              const float* __restrict__ bias,
                              float* __restrict__ hout,
                              float* __restrict__ dout, int last) {
  int g = blockIdx.x * 256 + threadIdx.x;
  if (g >= Vn * OUTD) return;
  float v = agg[g];
  agg[g] = 0.0f;
  float r = fmaxf(v + bias[g & 63], 0.0f);
  hout[g] = r;
  if (last) dout[g] = r;
}

extern "C" void kernel_launch(void* const* d_in, const int* in_sizes, int n_in,
                              void* d_out, int out_size, void* d_ws, size_t ws_size,
                              hipStream_t stream) {
  const float* node = (const float*)d_in[0];
  const float* edge = (const float*)d_in[1];
  const int* src = (const int*)d_in[2];
  const int* dst = (const int*)d_in[3];
  const float* Wp   = (const float*)d_in[4];
  const float* bp   = (const float*)d_in[5];
  const float* We1  = (const float*)d_in[6];
  const float* be1  = (const float*)d_in[7];
  const float* We2  = (const float*)d_in[8];
  const float* be2  = (const float*)d_in[9];
  const float* bias = (const float*)d_in[10];
  float* out = (float*)d_out;

  char* ws = (char*)d_ws;
  float* agg = (float*)(ws);                        // 6,400,000 B
  float* h_a = (float*)(ws + 6400000);              // 6,400,000 B
  float* h_b = (float*)(ws + 12800000);             // 6,400,000 B
  _Float16* f   = (_Float16*)(ws + 19200000);       // 25,600,000 B
  _Float16* w2s = (_Float16*)(ws + 44800000);       // 1,048,576 B

  hipMemsetAsync(agg, 0, (size_t)Vn * OUTD * sizeof(float), stream);
  proj_kernel<<<Vn, 64, 0, stream>>>(node, Wp, bp, h_a);
  edge_kernel<<<En, 128, 0, stream>>>(edge, We1, be1, f);
  w2r_kernel<<<(OUTD * OUTD * EHID) / 256, 256, 0, stream>>>(We2, w2s);

  float* hin = h_a;
  float* hout = h_b;
  for (int s = 0; s < NUM_STEPS; ++s) {
    msg_kernel<<<(En + 63) / 64, 256, 0, stream>>>(hin, f, w2s, src, dst, be2, agg);
    update_kernel<<<(Vn * OUTD + 255) / 256, 256, 0, stream>>>(
        agg, bias, hout, out, s == NUM_STEPS - 1);
    float* t = hin; hin = hout; hout = t;
  }
}